// Round 11
// baseline (40.585 us; speedup 1.0000x reference)
//
#include <hip/hip_runtime.h>
#include <hip/hip_bf16.h>
#include <math.h>

// QuadraticNetCholesky fused kernel, round 11.
// y = x^T (L L^T) x = ||L^T x||^2 ; v_j = sum_{i>=j} x_i * c[i(i+1)/2 + j].
// R11 = R9 structure (proven) + wcvt prologue folded in (single kernel).
// Weights convert fp32->bf16 in-register at frag load (scalar casts; the
// compiler fuses pairs into v_cvt_pk_bf16_f32). Softplus stays the PROVEN
// clamped form. R10's raw cvt_pk asm + unclamped softplus are reverted
// (one of them produced NaN).

constexpr int NI  = 24;
constexpr int H1  = 128;
constexpr int H2  = 32;
constexpr int SPB = 64;      // samples per block (128 threads, 2 waves)
constexpr int NT_TOT = 19;   // ceil(300/16) W3 row tiles
constexpr float LOG2E = 1.4426950408889634f;
constexpr float LN2SQ = 0.4804530139182014f;   // ln(2)^2

typedef __attribute__((ext_vector_type(8))) short bf16x8;
typedef __attribute__((ext_vector_type(4))) float f32x4;

struct TriMap { unsigned char i[320]; unsigned char j[320]; };
constexpr TriMap mk_map() {
    TriMap m{};
    int t = 0;
    for (int i = 0; i < NI; ++i)
        for (int j = 0; j <= i; ++j) { m.i[t] = (unsigned char)i; m.j[t] = (unsigned char)j; ++t; }
    for (; t < 320; ++t) { m.i[t] = 0; m.j[t] = 0; }
    return m;
}
constexpr TriMap TM = mk_map();

__device__ __forceinline__ float elu_f(float v) {
    return v > 0.0f ? v : __expf(v) - 1.0f;
}
__device__ __forceinline__ float exp2_hw(float x) {
    float r; asm("v_exp_f32 %0, %1" : "=v"(r) : "v"(x)); return r;
}
__device__ __forceinline__ float log2_hw(float x) {
    float r; asm("v_log_f32 %0, %1" : "=v"(r) : "v"(x)); return r;
}
// softplus(z)/ln2 with z' = z*log2e as input: max(z',0) + log2(1+2^-|z'|)
// (proven R6-R9 form; clamped, cannot overflow/NaN)
__device__ __forceinline__ float softplus_g(float zp) {
    return fmaxf(zp, 0.0f) + log2_hw(1.0f + exp2_hw(-fabsf(zp)));
}
__device__ __forceinline__ unsigned short f2bf(float f) {
    return __builtin_bit_cast(unsigned short, __float2bfloat16(f));
}
__device__ __forceinline__ unsigned int pk2(float a, float b) {
    return (unsigned int)f2bf(a) | ((unsigned int)f2bf(b) << 16);
}
// 8 contiguous fp32 -> bf16x8 fragment (2x float4 load + scalar casts;
// compiler pair-fuses to v_cvt_pk_bf16_f32)
__device__ __forceinline__ bf16x8 cvt8(const float* __restrict__ p) {
    float4 a = *reinterpret_cast<const float4*>(p);
    float4 b = *reinterpret_cast<const float4*>(p + 4);
    uint4 u = make_uint4(pk2(a.x, a.y), pk2(a.z, a.w), pk2(b.x, b.y), pk2(b.z, b.w));
    return __builtin_bit_cast(bf16x8, u);
}
// same, with pre-scale (W3*log2e, matching R9 table numerics)
__device__ __forceinline__ bf16x8 cvt8s(const float* __restrict__ p, float s) {
    float4 a = *reinterpret_cast<const float4*>(p);
    float4 b = *reinterpret_cast<const float4*>(p + 4);
    uint4 u = make_uint4(pk2(a.x * s, a.y * s), pk2(a.z * s, a.w * s),
                         pk2(b.x * s, b.y * s), pk2(b.z * s, b.w * s));
    return __builtin_bit_cast(bf16x8, u);
}

// consume 16 t-values [T0, T0+16) from own c_buf row; fully static indices.
template<int CH, int HF>
__device__ __forceinline__ void consume3(const float* __restrict__ crow,
                                         const float xr[NI], float v[NI]) {
    constexpr int T0 = CH * 32 + HF * 16;
    if constexpr (T0 < 300) {
        const f32x4* p = reinterpret_cast<const f32x4*>(crow + HF * 16);
        f32x4 cc[4];
        cc[0] = p[0]; cc[1] = p[1]; cc[2] = p[2]; cc[3] = p[3];
        #pragma unroll
        for (int tl = 0; tl < 16; ++tl) {
            if (T0 + tl < 300)
                v[TM.j[T0 + tl]] =
                    fmaf(xr[TM.i[T0 + tl]], cc[tl >> 2][tl & 3], v[TM.j[T0 + tl]]);
        }
    }
}

// one stage-3 chunk: produce 16 own-parity t-cols (all 64 samples), consume
// own row. Entirely wave-private: no __syncthreads.
template<int CH>
__device__ __forceinline__ void chunk3(
    int half, int lr, int lq, int lane,
    const float* __restrict__ W3, const float* __restrict__ b3,
    const float xr[NI], float v[NI],
    float* __restrict__ c_buf, const unsigned short* __restrict__ h2b)
{
    const int my_nt = 2 * CH + half;          // parity == half always
    if (my_nt < NT_TOT) {
        const int trow = my_nt * 16 + lr;
        // t >= 300: clamp row in-bounds; garbage values guarded in consume3.
        bf16x8 af = cvt8s(W3 + (trow < 300 ? trow : 299) * H2 + lq * 8, LOG2E);
        const int boff = my_nt * 16 + 4 * lq;
        const float4 b4 = *reinterpret_cast<const float4*>(b3 + (boff <= 296 ? boff : 296));
        f32x4 b4s;
        b4s[0] = b4.x * LOG2E; b4s[1] = b4.y * LOG2E;
        b4s[2] = b4.z * LOG2E; b4s[3] = b4.w * LOG2E;
        #pragma unroll
        for (int st = 0; st < 4; ++st) {
            bf16x8 hb = *reinterpret_cast<const bf16x8*>(h2b + (st * 16 + lr) * 40 + lq * 8);
            f32x4 a = {0.f, 0.f, 0.f, 0.f};
            a = __builtin_amdgcn_mfma_f32_16x16x32_bf16(af, hb, a, 0, 0, 0);
            // D: row(4lq+r)=t-in-tile, col(lane&15)=sample-in-st-tile
            f32x4 w;
            #pragma unroll
            for (int r = 0; r < 4; ++r)
                w[r] = softplus_g(a[r] + b4s[r]);
            *reinterpret_cast<f32x4*>(
                c_buf + (st * 16 + lr) * 36 + half * 16 + 4 * lq) = w;
        }
    }
    if (half == 0) consume3<CH, 0>(c_buf + lane * 36, xr, v);
    else           consume3<CH, 1>(c_buf + lane * 36, xr, v);
}

__global__ __launch_bounds__(128, 4) void qnet_fused(
    const float* __restrict__ x,
    const float* __restrict__ W1, const float* __restrict__ b1,
    const float* __restrict__ W2, const float* __restrict__ b2,
    const float* __restrict__ W3, const float* __restrict__ b3,
    float* __restrict__ y, int B)
{
    // Layout (bytes): h1s [64][40]sh @0..5120 (stages 1-2 only);
    // h2b [64][40]sh @9216..14336 (live through stage 3);
    // c_buf [64][36]f32 @0..9216 overlay (stage 3); vx [64][24]f32 @0 overlay.
    __shared__ __align__(16) unsigned char L[14336];
    unsigned short* h1s = reinterpret_cast<unsigned short*>(L);
    unsigned short* h2b = reinterpret_cast<unsigned short*>(L + 9216);
    float* c_buf = reinterpret_cast<float*>(L);
    float* vx    = reinterpret_cast<float*>(L);

    const int tid  = threadIdx.x;
    const int lane = tid & 63;               // == sample id within block
    const int lr   = lane & 15, lq = lane >> 4;
    const int half = __builtin_amdgcn_readfirstlane(tid >> 6);   // wave id
    const size_t sbase = (size_t)blockIdx.x * SPB;

    // ---- x of own sample, fp32 regs (for quadratic form) ----
    float xr[NI];
    {
        const float4* xp4 = reinterpret_cast<const float4*>(x + (sbase + lane) * NI);
        #pragma unroll
        for (int q = 0; q < NI / 4; ++q) {
            float4 t4 = xp4[q];
            xr[4*q+0] = t4.x; xr[4*q+1] = t4.y; xr[4*q+2] = t4.z; xr[4*q+3] = t4.w;
        }
    }

    // ---- stage-1 x B-frags: K-invariant, in regs. lq==3 is the K-pad
    // (matching W1 frag is zeroed) -> clamp pointer, values irrelevant.
    bf16x8 xf[2];
    #pragma unroll
    for (int u = 0; u < 2; ++u) {
        const int st = 2 * half + u;
        xf[u] = cvt8(x + (sbase + st * 16 + lr) * NI + (lq == 3 ? 0 : lq * 8));
    }

    // ---- stages 1+2, K-chunked by 32 h1-rows; wave-private (own 32 samples),
    // stage-2 partials in regs; NO barriers (intra-wave in-order LDS).
    f32x4 acc[2][2];
    #pragma unroll
    for (int u = 0; u < 2; ++u)
        #pragma unroll
        for (int n2 = 0; n2 < 2; ++n2) acc[u][n2] = (f32x4){0.f, 0.f, 0.f, 0.f};

    #pragma unroll
    for (int kk = 0; kk < 4; ++kk) {
        // stage 1: h1 rows [32kk, 32kk+32) for own 32 samples
        #pragma unroll
        for (int n = 0; n < 2; ++n) {
            const int nt1 = 2 * kk + n;
            bf16x8 af;
            if (lq == 3) af = (bf16x8){0,0,0,0,0,0,0,0};          // K-pad rows
            else         af = cvt8(W1 + (nt1 * 16 + lr) * NI + lq * 8);
            const float4 bb1 = *reinterpret_cast<const float4*>(b1 + nt1 * 16 + 4 * lq);
            #pragma unroll
            for (int u = 0; u < 2; ++u) {
                const int st = 2 * half + u;
                f32x4 a = {0.f, 0.f, 0.f, 0.f};
                a = __builtin_amdgcn_mfma_f32_16x16x32_bf16(af, xf[u], a, 0, 0, 0);
                unsigned int p0 = pk2(elu_f(a[0] + bb1.x), elu_f(a[1] + bb1.y));
                unsigned int p1 = pk2(elu_f(a[2] + bb1.z), elu_f(a[3] + bb1.w));
                unsigned long long pw = (unsigned long long)p0 | ((unsigned long long)p1 << 32);
                // sample = st*16+lr (own range); local col = n*16 + 4lq + r
                *reinterpret_cast<unsigned long long*>(
                    h1s + (st * 16 + lr) * 40 + n * 16 + 4 * lq) = pw;
            }
        }
        // stage 2: accumulate this K-chunk (reads only own rows)
        #pragma unroll
        for (int u = 0; u < 2; ++u) {
            const int st2 = 2 * half + u;
            bf16x8 hb = *reinterpret_cast<const bf16x8*>(h1s + (st2 * 16 + lr) * 40 + lq * 8);
            #pragma unroll
            for (int n2 = 0; n2 < 2; ++n2) {
                bf16x8 wf = cvt8(W2 + (n2 * 16 + lr) * H1 + kk * 32 + lq * 8);
                acc[u][n2] = __builtin_amdgcn_mfma_f32_16x16x32_bf16(wf, hb, acc[u][n2], 0, 0, 0);
            }
        }
    }

    // ---- finish h2: elu + bias, pack bf16 to h2b (own samples) ----
    #pragma unroll
    for (int u = 0; u < 2; ++u) {
        const int st2 = 2 * half + u;
        #pragma unroll
        for (int n2 = 0; n2 < 2; ++n2) {
            const float4 bb2 = *reinterpret_cast<const float4*>(b2 + n2 * 16 + 4 * lq);
            unsigned int p0 = pk2(elu_f(acc[u][n2][0] + bb2.x), elu_f(acc[u][n2][1] + bb2.y));
            unsigned int p1 = pk2(elu_f(acc[u][n2][2] + bb2.z), elu_f(acc[u][n2][3] + bb2.w));
            unsigned long long pw = (unsigned long long)p0 | ((unsigned long long)p1 << 32);
            *reinterpret_cast<unsigned long long*>(
                h2b + (st2 * 16 + lr) * 40 + n2 * 16 + 4 * lq) = pw;
        }
    }
    __syncthreads();   // barrier 1/3: h2b cross-wave; h1s dead -> c_buf region

    // ---- stage 3: 10 chunks, fully wave-private (no barriers) ----
    float v[NI];
    #pragma unroll
    for (int q = 0; q < NI; ++q) v[q] = 0.f;

    chunk3<0>(half, lr, lq, lane, W3, b3, xr, v, c_buf, h2b);
    chunk3<1>(half, lr, lq, lane, W3, b3, xr, v, c_buf, h2b);
    chunk3<2>(half, lr, lq, lane, W3, b3, xr, v, c_buf, h2b);
    chunk3<3>(half, lr, lq, lane, W3, b3, xr, v, c_buf, h2b);
    chunk3<4>(half, lr, lq, lane, W3, b3, xr, v, c_buf, h2b);
    chunk3<5>(half, lr, lq, lane, W3, b3, xr, v, c_buf, h2b);
    chunk3<6>(half, lr, lq, lane, W3, b3, xr, v, c_buf, h2b);
    chunk3<7>(half, lr, lq, lane, W3, b3, xr, v, c_buf, h2b);
    chunk3<8>(half, lr, lq, lane, W3, b3, xr, v, c_buf, h2b);
    chunk3<9>(half, lr, lq, lane, W3, b3, xr, v, c_buf, h2b);

    // ---- combine partial v across waves; y = ln2^2 * sum v_j^2 ----
    __syncthreads();   // barrier 2/3: all consumes done before vx overlay
    if (half == 1) {
        f32x4* dst = reinterpret_cast<f32x4*>(vx + lane * 24);
        #pragma unroll
        for (int q = 0; q < 6; ++q) {
            f32x4 t4 = { v[4*q], v[4*q+1], v[4*q+2], v[4*q+3] };
            dst[q] = t4;
        }
    }
    __syncthreads();   // barrier 3/3
    if (half == 0) {
        const f32x4* src = reinterpret_cast<const f32x4*>(vx + lane * 24);
        float acc_y = 0.f;
        #pragma unroll
        for (int q = 0; q < 6; ++q) {
            f32x4 t4 = src[q];
            #pragma unroll
            for (int r = 0; r < 4; ++r) {
                float sv = v[4*q + r] + t4[r];
                acc_y = fmaf(sv, sv, acc_y);
            }
        }
        y[sbase + lane] = LN2SQ * acc_y;
    }
}

extern "C" void kernel_launch(void* const* d_in, const int* in_sizes, int n_in,
                              void* d_out, int out_size, void* d_ws, size_t ws_size,
                              hipStream_t stream) {
    const float* x  = (const float*)d_in[0];
    const float* W1 = (const float*)d_in[1];
    const float* b1 = (const float*)d_in[2];
    const float* W2 = (const float*)d_in[3];
    const float* b2 = (const float*)d_in[4];
    const float* W3 = (const float*)d_in[5];
    const float* b3 = (const float*)d_in[6];
    float* y = (float*)d_out;

    const int B = in_sizes[0] / NI;   // 131072, divisible by SPB
    qnet_fused<<<dim3(B / SPB), dim3(128), 0, stream>>>(
        x, W1, b1, W2, b2, W3, b3, y, B);
}